// Round 1
// 515.826 us; speedup vs baseline: 1.0054x; 1.0054x over previous
//
#include <hip/hip_runtime.h>
#include <hip/hip_bf16.h>

#define B   512
#define C   512
#define HW  240
#define HW4 60    // HW/4
#define E   128
#define XD  640   // C + E
#define G3  1536  // 3*C

typedef short  s8v  __attribute__((ext_vector_type(8)));
typedef float  f4v  __attribute__((ext_vector_type(4)));

__device__ __forceinline__ float fast_tanh(float x) {
    float ex = __expf(2.0f * x);
    return (ex - 1.0f) * __builtin_amdgcn_rcpf(ex + 1.0f);
}
__device__ __forceinline__ float fast_sigmoid(float x) {
    return __builtin_amdgcn_rcpf(1.0f + __expf(-x));
}
__device__ __forceinline__ unsigned short f2bf(float x) {
    return __builtin_bit_cast(unsigned short, __float2bfloat16(x));
}
__device__ __forceinline__ s8v pack8(float4 a, float4 b) {
    s8v o;
    o[0] = (short)f2bf(a.x); o[1] = (short)f2bf(a.y);
    o[2] = (short)f2bf(a.z); o[3] = (short)f2bf(a.w);
    o[4] = (short)f2bf(b.x); o[5] = (short)f2bf(b.y);
    o[6] = (short)f2bf(b.z); o[7] = (short)f2bf(b.w);
    return o;
}

// ---------------- K12: fused emition + softmax + context ---------------------
// grid (B), 512 threads (8 waves). One block owns batch element b end-to-end.
// Phase A: wave g sums rows [64g, 64g+64) of tanh(cf+ph)*sw into LDS partials.
//   Uses shift-invariance: sw*tanh(u) = sw - 2sw/(e^{2u}+1); the sw constant
//   is h-independent and cancels in softmax, so accumulate only -2sw*rcp(...).
// Softmax: wave 0 only (240 vals = 60 float4 across 60 lanes, shfl reduce).
// Phase B: context = cfo . alpha, 4 lanes/row, 128 rows/pass, 4 passes.
__global__ __launch_bounds__(512) void attn_kernel(
    const float* __restrict__ prev_hidden,   // [B, C]
    const float* __restrict__ conv_feats,    // [B, C, HW]
    const float* __restrict__ cfo,           // [B, C, HW]
    const float* __restrict__ cur_emb,       // [B, E]
    const float* __restrict__ score_w,       // [C]
    float* __restrict__ alpha_out,           // [HW, B]
    unsigned short* __restrict__ x_bf16)     // [B, XD]
{
    const int b    = blockIdx.x;
    const int t    = threadIdx.x;
    const int w    = t >> 6;
    const int lane = t & 63;

    __shared__ float ph2_s[C];      // 2*prev_hidden
    __shared__ float msw_s[C];      // -2*score_w
    __shared__ f4v   red[8][HW4];   // per-wave partial emition
    __shared__ f4v   af4[HW4];      // alpha

    // stage params (512 threads == C)
    ph2_s[t] = 2.0f * prev_hidden[(size_t)b * C + t];
    msw_s[t] = -2.0f * score_w[t];
    // embedding slice of x (independent of everything else)
    if (t < E) x_bf16[(size_t)b * XD + C + t] = f2bf(cur_emb[(size_t)b * E + t]);
    __syncthreads();

    // --- phase A: emition partials -------------------------------------------
    {
        const int g = w;          // row-group: rows [64g, 64g+64)
        const int i = lane;       // float4 column
        f4v acc = {0.f, 0.f, 0.f, 0.f};
        if (i < HW4) {
            const float4* cf4 = (const float4*)conv_feats
                              + (size_t)(b * C + g * 64) * HW4 + i;
            #pragma unroll 8
            for (int j = 0; j < 64; ++j) {
                float4 v  = cf4[(size_t)j * HW4];
                float ph2 = ph2_s[g * 64 + j];
                float msw = msw_s[g * 64 + j];
                acc[0] += msw * __builtin_amdgcn_rcpf(__expf(fmaf(v.x, 2.0f, ph2)) + 1.0f);
                acc[1] += msw * __builtin_amdgcn_rcpf(__expf(fmaf(v.y, 2.0f, ph2)) + 1.0f);
                acc[2] += msw * __builtin_amdgcn_rcpf(__expf(fmaf(v.z, 2.0f, ph2)) + 1.0f);
                acc[3] += msw * __builtin_amdgcn_rcpf(__expf(fmaf(v.w, 2.0f, ph2)) + 1.0f);
            }
            red[g][i] = acc;
        }
    }
    __syncthreads();

    // --- softmax (wave 0 only) -----------------------------------------------
    if (w == 0) {
        const bool act = lane < HW4;
        f4v e4 = {0.f, 0.f, 0.f, 0.f};
        if (act) {
            #pragma unroll
            for (int g = 0; g < 8; ++g) {
                f4v r = red[g][lane];
                e4[0] += r[0]; e4[1] += r[1]; e4[2] += r[2]; e4[3] += r[3];
            }
        }
        float mx = act ? fmaxf(fmaxf(e4[0], e4[1]), fmaxf(e4[2], e4[3])) : -1e30f;
        #pragma unroll
        for (int off = 32; off >= 1; off >>= 1) mx = fmaxf(mx, __shfl_xor(mx, off));

        f4v p4;
        p4[0] = act ? __expf(e4[0] - mx) : 0.f;
        p4[1] = act ? __expf(e4[1] - mx) : 0.f;
        p4[2] = act ? __expf(e4[2] - mx) : 0.f;
        p4[3] = act ? __expf(e4[3] - mx) : 0.f;
        float s = p4[0] + p4[1] + p4[2] + p4[3];
        #pragma unroll
        for (int off = 32; off >= 1; off >>= 1) s += __shfl_xor(s, off);
        float inv = __builtin_amdgcn_rcpf(s);

        if (act) {
            f4v a;
            a[0] = p4[0] * inv; a[1] = p4[1] * inv;
            a[2] = p4[2] * inv; a[3] = p4[3] * inv;
            af4[lane] = a;
            float* ao = alpha_out + b;
            ao[(size_t)(4 * lane + 0) * B] = a[0];
            ao[(size_t)(4 * lane + 1) * B] = a[1];
            ao[(size_t)(4 * lane + 2) * B] = a[2];
            ao[(size_t)(4 * lane + 3) * B] = a[3];
        }
    }
    __syncthreads();

    // --- phase B: context ----------------------------------------------------
    const int r0 = (w << 4) + (lane >> 2);   // [0,128)
    const int q  = lane & 3;
    #pragma unroll
    for (int p = 0; p < 4; ++p) {
        const int r = p * 128 + r0;
        const float4* row = (const float4*)cfo + (size_t)(b * C + r) * HW4;
        float acc = 0.f;
        #pragma unroll
        for (int k = 0; k < 15; ++k) {
            float4 v = row[q + 4 * k];
            f4v   av = af4[q + 4 * k];
            acc += v.x * av[0] + v.y * av[1] + v.z * av[2] + v.w * av[3];
        }
        acc += __shfl_xor(acc, 1);
        acc += __shfl_xor(acc, 2);
        if (q == 0) x_bf16[(size_t)b * XD + r] = f2bf(acc);
    }
}

// ---------------- K3: GEMM with inline f32->bf16 staging ---------------------
// G[b,j] = sum_k A[b,k] * W[j,k] + bias[j]
// z=0: gi = x(bf16) @ w_ih(f32)^T, K=640.  z=1: gh = h(f32) @ w_hh(f32)^T, K=512.
__global__ __launch_bounds__(256) void gemm_kernel(
    const unsigned short* __restrict__ x,   // [B, XD] bf16
    const float* __restrict__ hprev,        // [B, C]  f32
    const float* __restrict__ wih,          // [G3, XD] f32
    const float* __restrict__ whh,          // [G3, C]  f32
    const float* __restrict__ b_ih, const float* __restrict__ b_hh,
    float* __restrict__ gi, float* __restrict__ gh)
{
    const int z = blockIdx.z;
    const float* Wmat = z ? whh : wih;
    const float* bias = z ? b_hh : b_ih;
    float* out = z ? gh : gi;
    const int K = z ? C : XD;

    const int b0 = blockIdx.x * 64;
    const int j0 = blockIdx.y * 64;

    __shared__ alignas(16) unsigned short As[64][72]; // 144B row stride
    __shared__ alignas(16) unsigned short Ws[64][72];

    const int t = threadIdx.x, lane = t & 63, w = t >> 6;
    const int wm = w & 1, wn = w >> 1;
    const int r = t >> 2, col0 = (t & 3) * 16;
    const int q = lane >> 4, mm = lane & 15;

    f4v z4 = {0.f, 0.f, 0.f, 0.f};
    f4v acc[2][2] = {{z4, z4}, {z4, z4}};

    for (int k0 = 0; k0 < K; k0 += 64) {
        s8v a0, a1, w0, w1;
        if (z) {
            const float4* pa = (const float4*)&hprev[(size_t)(b0 + r) * C + k0 + col0];
            float4 f0 = pa[0], f1 = pa[1], f2 = pa[2], f3 = pa[3];
            a0 = pack8(f0, f1); a1 = pack8(f2, f3);
        } else {
            const unsigned short* pa = &x[(size_t)(b0 + r) * XD + k0 + col0];
            a0 = *(const s8v*)pa; a1 = *(const s8v*)(pa + 8);
        }
        {
            const float4* pw = (const float4*)&Wmat[(size_t)(j0 + r) * K + k0 + col0];
            float4 f0 = pw[0], f1 = pw[1], f2 = pw[2], f3 = pw[3];
            w0 = pack8(f0, f1); w1 = pack8(f2, f3);
        }
        __syncthreads();
        *(s8v*)&As[r][col0]     = a0;
        *(s8v*)&As[r][col0 + 8] = a1;
        *(s8v*)&Ws[r][col0]     = w0;
        *(s8v*)&Ws[r][col0 + 8] = w1;
        __syncthreads();

        #pragma unroll
        for (int kk = 0; kk < 2; ++kk) {
            s8v av0 = *(const s8v*)&As[wm * 32 + mm][kk * 32 + q * 8];
            s8v av1 = *(const s8v*)&As[wm * 32 + 16 + mm][kk * 32 + q * 8];
            s8v wv0 = *(const s8v*)&Ws[wn * 32 + mm][kk * 32 + q * 8];
            s8v wv1 = *(const s8v*)&Ws[wn * 32 + 16 + mm][kk * 32 + q * 8];
            acc[0][0] = __builtin_amdgcn_mfma_f32_16x16x32_bf16(av0, wv0, acc[0][0], 0, 0, 0);
            acc[0][1] = __builtin_amdgcn_mfma_f32_16x16x32_bf16(av0, wv1, acc[0][1], 0, 0, 0);
            acc[1][0] = __builtin_amdgcn_mfma_f32_16x16x32_bf16(av1, wv0, acc[1][0], 0, 0, 0);
            acc[1][1] = __builtin_amdgcn_mfma_f32_16x16x32_bf16(av1, wv1, acc[1][1], 0, 0, 0);
        }
    }

    #pragma unroll
    for (int mi = 0; mi < 2; ++mi)
        #pragma unroll
        for (int ni = 0; ni < 2; ++ni) {
            int jj = j0 + wn * 32 + ni * 16 + mm;
            float bv = bias[jj];
            #pragma unroll
            for (int rg = 0; rg < 4; ++rg) {
                int bi = b0 + wm * 32 + mi * 16 + q * 4 + rg;
                out[(size_t)bi * G3 + jj] = acc[mi][ni][rg] + bv;
            }
        }
}

// ---------------- K4: GRU gates ----------------------------------------------
__global__ void gates_kernel(const float* __restrict__ gi,
                             const float* __restrict__ gh,
                             const float* __restrict__ hprev,
                             float* __restrict__ out)
{
    int idx = blockIdx.x * blockDim.x + threadIdx.x;
    if (idx >= B * C) return;
    int b = idx >> 9;
    int c = idx & 511;
    const float* gib = gi + (size_t)b * G3;
    const float* ghb = gh + (size_t)b * G3;
    float r  = fast_sigmoid(gib[c] + ghb[c]);
    float zz = fast_sigmoid(gib[c + C] + ghb[c + C]);
    float n  = fast_tanh(gib[c + 2 * C] + r * ghb[c + 2 * C]);
    out[idx] = (1.f - zz) * n + zz * hprev[idx];
}

// ---------------- launch -----------------------------------------------------
extern "C" void kernel_launch(void* const* d_in, const int* in_sizes, int n_in,
                              void* d_out, int out_size, void* d_ws, size_t ws_size,
                              hipStream_t stream)
{
    const float* prev_hidden = (const float*)d_in[0];
    const float* conv_feats  = (const float*)d_in[1];
    const float* cfo         = (const float*)d_in[2];
    const float* emb         = (const float*)d_in[3];
    const float* score_w     = (const float*)d_in[4];
    const float* w_ih        = (const float*)d_in[5];
    const float* w_hh        = (const float*)d_in[6];
    const float* b_ih        = (const float*)d_in[7];
    const float* b_hh        = (const float*)d_in[8];

    float* out       = (float*)d_out;
    float* alpha_out = out + B * C;   // output 1: alpha.T [HW, B]

    char* ws = (char*)d_ws;
    float* gi              = (float*)(ws);                    // 512*1536*4 = 3,145,728
    float* gh              = (float*)(ws + 3145728);          // 3,145,728
    unsigned short* x_bf16 = (unsigned short*)(ws + 6291456); //   655,360 (end ~6.9 MB)

    attn_kernel<<<dim3(B), 512, 0, stream>>>(prev_hidden, conv_feats, cfo, emb,
                                             score_w, alpha_out, x_bf16);
    gemm_kernel<<<dim3(8, 24, 2), 256, 0, stream>>>(x_bf16, prev_hidden, w_ih, w_hh,
                                                    b_ih, b_hh, gi, gh);
    gates_kernel<<<(B * C + 255) / 256, 256, 0, stream>>>(gi, gh, prev_hidden, out);
}